// Round 2
// baseline (21818.491 us; speedup 1.0000x reference)
//
#include <hip/hip_runtime.h>

typedef __bf16 bf16_t;
typedef __bf16 bf16x8 __attribute__((ext_vector_type(8)));
typedef float f32x4 __attribute__((ext_vector_type(4)));

#define S_LEN 512
#define BATCH 64
#define HID 1024
#define BH (BATCH*HID)
#define G4 (4*HID)
#define NBLK 256
#define NTHR 256

__device__ __forceinline__ float sigmoid_f(float x) { return 1.f / (1.f + __expf(-x)); }
__device__ __forceinline__ float tanh_f(float x) {
    float e = __expf(-2.f * fabsf(x));
    float t = (1.f - e) / (1.f + e);
    return x >= 0.f ? t : -t;
}

__device__ __forceinline__ bf16x8 cvt8(const float* p) {
    float4 a = *reinterpret_cast<const float4*>(p);
    float4 b = *reinterpret_cast<const float4*>(p + 4);
    bf16x8 r;
    r[0] = (bf16_t)a.x; r[1] = (bf16_t)a.y; r[2] = (bf16_t)a.z; r[3] = (bf16_t)a.w;
    r[4] = (bf16_t)b.x; r[5] = (bf16_t)b.y; r[6] = (bf16_t)b.z; r[7] = (bf16_t)b.w;
    return r;
}

// prep: zero barrier state, prefill bf16 h-rings (slot 1) with cvt(h0).
__global__ void prep_kernel(const float* __restrict__ h0,
                            bf16_t* __restrict__ ring0, bf16_t* __restrict__ ring1,
                            unsigned* flags, unsigned* gen) {
    int i = blockIdx.x * 256 + threadIdx.x;      // 0..65535 == BH
    ring0[BH + i] = (bf16_t)h0[i];               // layer-0 h_{-1} -> slot 1
    ring1[BH + i] = (bf16_t)h0[BH + i];          // layer-1 h_{-1} -> slot 1
    if (blockIdx.x == 0) {
        flags[threadIdx.x] = 0u;
        if (threadIdx.x == 0) *gen = 0u;
    }
}

// Persistent LSTM, fp32 I/O, bf16 MFMA internals. 256 blocks (1/CU); block owns
// hidden units [4*bid, 4*bid+4) of the active layer; LDS = 16 gate rows x 2048 bf16.
__global__ __launch_bounds__(NTHR) void lstm_persistent(
    const float* __restrict__ x,
    const float* __restrict__ h0,
    const float* __restrict__ c0,
    const float* __restrict__ Wx,
    const float* __restrict__ Wh,
    const float* __restrict__ bx,
    const float* __restrict__ bh,
    float* __restrict__ out,
    bf16_t* __restrict__ ring0,
    bf16_t* __restrict__ ring1,
    unsigned* __restrict__ flags,
    unsigned* __restrict__ gen)
{
    __shared__ __attribute__((aligned(16))) unsigned char lds_w[16 * 4096]; // 64 KB

    const int tid  = threadIdx.x;
    const int bid  = blockIdx.x;
    const int lane = tid & 63;
    const int wv   = tid >> 6;
    const int quad = lane >> 4;
    const int r16  = lane & 15;
    const int swz  = r16 & 7;

    float* ys   = out;
    float* hfin = out + (size_t)S_LEN * BH;
    float* cfin = hfin + 2 * BH;

    const int b_loc  = lane >> 2;
    const int uu     = lane & 3;
    const int b_glob = 16 * wv + b_loc;
    const int gcol   = 4 * bid + uu;

    unsigned bargen = 0;
    float prev_h = 0.f;

    for (int l = 0; l < 2; ++l) {
        // ---- stage weights (fp32 -> bf16) into LDS, XOR-swizzled 16B granules ----
        {
            const float* WxL = Wx + (size_t)l * G4 * HID;
            const float* WhL = Wh + (size_t)l * G4 * HID;
            for (int ch = tid; ch < 16 * 256; ch += NTHR) {
                int row = ch >> 8;
                int off = ch & 255;
                int g = row >> 2, u = row & 3;
                size_t R = (size_t)g * HID + 4 * bid + u;
                const float* src = (off < 128) ? (WxL + R * HID + (size_t)off * 8)
                                               : (WhL + R * HID + (size_t)(off - 128) * 8);
                bf16x8 v = cvt8(src);
                *reinterpret_cast<bf16x8*>(&lds_w[(row << 12) + ((off ^ (row & 7)) << 4)]) = v;
            }
        }
        float bias_r[4];
        #pragma unroll
        for (int gi = 0; gi < 4; ++gi) {
            int R = gi * HID + gcol;
            bias_r[gi] = bx[l * G4 + R] + bh[l * G4 + R];
        }
        float c_reg = c0[(size_t)l * BH + (size_t)b_glob * HID + gcol];
        bf16_t* ringL = (l == 0) ? ring0 : ring1;
        __syncthreads();

        for (int t = 0; t < S_LEN; ++t) {
            // x-part: fp32 (input x for layer 0, ys history for layer 1)
            const float*  Ax32 = (l == 0) ? (x + (size_t)t * BH) : (ys + (size_t)t * BH);
            // h-part: bf16 ring (slot 1 prefilled with h0 for t==0; (-1)&1 == 1)
            const bf16_t* Ah   = ringL + (size_t)((t - 1) & 1) * BH;

            f32x4 acc = {0.f, 0.f, 0.f, 0.f};
            const float*  arow32 = Ax32 + (size_t)(16 * wv + r16) * HID + quad * 8;
            const bf16_t* arow16 = Ah   + (size_t)(16 * wv + r16) * HID + quad * 8;
            const unsigned char* bbase = &lds_w[r16 << 12];
            #pragma unroll 4
            for (int kb = 0; kb < 32; ++kb) {
                int gk = (kb << 2) + quad;
                bf16x8 bfrag = *reinterpret_cast<const bf16x8*>(bbase + ((gk ^ swz) << 4));
                bf16x8 afrag = cvt8(arow32 + (kb << 5));
                acc = __builtin_amdgcn_mfma_f32_16x16x32_bf16(afrag, bfrag, acc, 0, 0, 0);
            }
            #pragma unroll 4
            for (int kb = 0; kb < 32; ++kb) {
                int gk = 128 + (kb << 2) + quad;
                bf16x8 bfrag = *reinterpret_cast<const bf16x8*>(bbase + ((gk ^ swz) << 4));
                bf16x8 afrag = *reinterpret_cast<const bf16x8*>(arow16 + (kb << 5));
                acc = __builtin_amdgcn_mfma_f32_16x16x32_bf16(afrag, bfrag, acc, 0, 0, 0);
            }

            // gather 4 gates for (b_loc, uu): C layout col=lane&15, row=quad*4+reg
            const int quad_s = b_loc >> 2;
            const int reg_s  = b_loc & 3;
            float gsum[4];
            #pragma unroll
            for (int gi = 0; gi < 4; ++gi) {
                int lane_s = (quad_s << 4) | (4 * gi + uu);
                float v0 = __shfl(acc[0], lane_s, 64);
                float v1 = __shfl(acc[1], lane_s, 64);
                float v2 = __shfl(acc[2], lane_s, 64);
                float v3 = __shfl(acc[3], lane_s, 64);
                float v  = (reg_s == 0) ? v0 : (reg_s == 1) ? v1 : (reg_s == 2) ? v2 : v3;
                gsum[gi] = v + bias_r[gi];
            }
            float fg = sigmoid_f(gsum[0]);
            float ig = sigmoid_f(gsum[1]);
            float og = sigmoid_f(gsum[2]);
            float cx = tanh_f(gsum[3]);
            float cN = fg * c_reg + ig * cx;
            float h  = og * tanh_f(cN);
            c_reg = cN;

            size_t ridx = (size_t)(t & 1) * BH + (size_t)b_glob * HID + gcol;
            size_t oidx = (size_t)t * BH + (size_t)b_glob * HID + gcol;
            ringL[ridx] = (bf16_t)h;                       // bf16 recurrence copy
            if (l == 0) {
                ys[oidx] = h;                              // fp32 h^0 history for layer 1
            } else {
                if (t > 0) ys[oidx - BH] = prev_h;         // deferred overwrite, no reader now
                prev_h = h;
            }
            if (t == S_LEN - 1) {
                hfin[(size_t)l * BH + (size_t)b_glob * HID + gcol] = h;
                cfin[(size_t)l * BH + (size_t)b_glob * HID + gcol] = cN;
            }

            // ---- grid barrier ----
            ++bargen;
            __syncthreads();
            if (tid == 0) {
                __builtin_amdgcn_fence(__ATOMIC_RELEASE, "agent");
                __hip_atomic_store(&flags[bid], bargen, __ATOMIC_RELAXED, __HIP_MEMORY_SCOPE_AGENT);
            }
            if (bid == 0) {
                if (tid < 64) {
                    for (;;) {
                        unsigned m0 = __hip_atomic_load(&flags[tid],       __ATOMIC_RELAXED, __HIP_MEMORY_SCOPE_AGENT);
                        unsigned m1 = __hip_atomic_load(&flags[tid + 64],  __ATOMIC_RELAXED, __HIP_MEMORY_SCOPE_AGENT);
                        unsigned m2 = __hip_atomic_load(&flags[tid + 128], __ATOMIC_RELAXED, __HIP_MEMORY_SCOPE_AGENT);
                        unsigned m3 = __hip_atomic_load(&flags[tid + 192], __ATOMIC_RELAXED, __HIP_MEMORY_SCOPE_AGENT);
                        bool ok = (m0 >= bargen) && (m1 >= bargen) && (m2 >= bargen) && (m3 >= bargen);
                        if (__all(ok)) break;
                        __builtin_amdgcn_s_sleep(1);
                    }
                    if (tid == 0)
                        __hip_atomic_store(gen, bargen, __ATOMIC_RELAXED, __HIP_MEMORY_SCOPE_AGENT);
                }
            } else if (tid == 0) {
                while (__hip_atomic_load(gen, __ATOMIC_RELAXED, __HIP_MEMORY_SCOPE_AGENT) < bargen)
                    __builtin_amdgcn_s_sleep(1);
            }
            if (tid == 0 || (bid == 0 && tid < 64))
                __builtin_amdgcn_fence(__ATOMIC_ACQUIRE, "agent");
            __syncthreads();
        }
    }
    // tail: last deferred ys write for layer 1
    ys[(size_t)(S_LEN - 1) * BH + (size_t)b_glob * HID + gcol] = prev_h;
}

extern "C" void kernel_launch(void* const* d_in, const int* in_sizes, int n_in,
                              void* d_out, int out_size, void* d_ws, size_t ws_size,
                              hipStream_t stream) {
    (void)in_sizes; (void)n_in; (void)out_size; (void)ws_size;
    const float* x  = (const float*)d_in[0];
    const float* h0 = (const float*)d_in[1];
    const float* c0 = (const float*)d_in[2];
    const float* Wx = (const float*)d_in[3];
    const float* Wh = (const float*)d_in[4];
    const float* bx = (const float*)d_in[5];
    const float* bh = (const float*)d_in[6];

    unsigned char* ws = (unsigned char*)d_ws;
    unsigned* flags = (unsigned*)ws;                         // 1 KB
    unsigned* gen   = (unsigned*)(ws + 1024);
    bf16_t*   ring0 = (bf16_t*)(ws + 4096);                  // 2*BH bf16 = 256 KB
    bf16_t*   ring1 = (bf16_t*)(ws + 4096 + 2 * BH * 2);     // 2*BH bf16 = 256 KB

    prep_kernel<<<256, 256, 0, stream>>>(h0, ring0, ring1, flags, gen);
    lstm_persistent<<<NBLK, NTHR, 0, stream>>>(x, h0, c0, Wx, Wh, bx, bh,
                                               (float*)d_out, ring0, ring1, flags, gen);
}

// Round 3
// 17732.277 us; speedup vs baseline: 1.2304x; 1.2304x over previous
//
#include <hip/hip_runtime.h>

typedef __bf16 bf16_t;
typedef __bf16 bf16x8 __attribute__((ext_vector_type(8)));
typedef float f32x4 __attribute__((ext_vector_type(4)));

#define S_LEN 512
#define BATCH 64
#define HID 1024
#define BH (BATCH*HID)          /* 65536 */
#define G4 (4*HID)
#define NBLK 512                /* 2 blocks/CU: 256 layer-0 + 256 layer-1 */
#define NTHR 256
#define FSTRIDE 16              /* flag padding: 64 B apart */

__device__ __forceinline__ float sigmoid_f(float x) { return 1.f / (1.f + __expf(-x)); }
__device__ __forceinline__ float tanh_f(float x) {
    float e = __expf(-2.f * fabsf(x));
    float t = (1.f - e) / (1.f + e);
    return x >= 0.f ? t : -t;
}

__device__ __forceinline__ bf16x8 cvt8(const float* p) {
    float4 a = *reinterpret_cast<const float4*>(p);
    float4 b = *reinterpret_cast<const float4*>(p + 4);
    bf16x8 r;
    r[0] = (bf16_t)a.x; r[1] = (bf16_t)a.y; r[2] = (bf16_t)a.z; r[3] = (bf16_t)a.w;
    r[4] = (bf16_t)b.x; r[5] = (bf16_t)b.y; r[6] = (bf16_t)b.z; r[7] = (bf16_t)b.w;
    return r;
}

// prep: zero barrier flags, prefill bf16 h-rings (slot 1 = h_{-1}), optional x->bf16 shadow.
__global__ void prep_kernel(const float* __restrict__ x, const float* __restrict__ h0,
                            bf16_t* __restrict__ ring0, bf16_t* __restrict__ ring1,
                            bf16_t* __restrict__ x_sh, unsigned* __restrict__ flags,
                            int use_xsh) {
    int gtid = blockIdx.x * blockDim.x + threadIdx.x;
    int gsz  = gridDim.x * blockDim.x;
    for (int i = gtid; i < NBLK * FSTRIDE; i += gsz) flags[i] = 0u;
    for (int i = gtid; i < BH; i += gsz) {
        ring0[BH + i] = (bf16_t)h0[i];
        ring1[BH + i] = (bf16_t)h0[BH + i];
    }
    if (use_xsh) {
        int ngrp = S_LEN * BH / 8;
        for (int g = gtid; g < ngrp; g += gsz)
            *reinterpret_cast<bf16x8*>(x_sh + (size_t)g * 8) = cvt8(x + (size_t)g * 8);
    }
}

// Persistent skewed LSTM. Block b: layer l=b>>8, unit-group ug=b&255 (hidden units 4ug..4ug+3).
// LDS: 16 gate rows x 2048 K bf16 = 64 KB (granules 0-127 = Wx_l, 128-255 = Wh_l).
// Interval i: layer-0 blocks compute t=i (i<512); layer-1 blocks compute t=i-1 (i>=1).
__global__ __launch_bounds__(NTHR) void lstm_persistent(
    const float* __restrict__ x,
    const float* __restrict__ c0,
    const float* __restrict__ Wx,
    const float* __restrict__ Wh,
    const float* __restrict__ bx,
    const float* __restrict__ bh,
    float* __restrict__ out,
    bf16_t* __restrict__ ring0,
    bf16_t* __restrict__ ring1,
    const bf16_t* __restrict__ x_sh,
    unsigned* __restrict__ flags,
    int use_xsh)
{
    __shared__ __attribute__((aligned(16))) unsigned char lds_w[16 * 4096]; // 64 KB

    const int tid  = threadIdx.x;
    const int bid  = blockIdx.x;
    const int l    = bid >> 8;          // layer this block owns
    const int ug   = bid & 255;         // unit group
    const int lane = tid & 63;
    const int wv   = tid >> 6;          // wave: batches [16*wv, 16*wv+16)
    const int quad = lane >> 4;
    const int r16  = lane & 15;
    const int swz  = r16 & 7;

    float* ys   = out;
    float* hfin = out + (size_t)S_LEN * BH;
    float* cfin = hfin + 2 * BH;

    const int b_loc  = lane >> 2;
    const int uu     = lane & 3;
    const int b_glob = 16 * wv + b_loc;
    const int gcol   = 4 * ug + uu;

    // ---- stage this layer's weight rows (fp32 -> bf16) into LDS ----
    {
        const float* WxL = Wx + (size_t)l * G4 * HID;
        const float* WhL = Wh + (size_t)l * G4 * HID;
        for (int ch = tid; ch < 16 * 256; ch += NTHR) {
            int row = ch >> 8;
            int off = ch & 255;
            int g = row >> 2, u = row & 3;
            size_t R = (size_t)g * HID + 4 * ug + u;
            const float* src = (off < 128) ? (WxL + R * HID + (size_t)off * 8)
                                           : (WhL + R * HID + (size_t)(off - 128) * 8);
            bf16x8 v = cvt8(src);
            *reinterpret_cast<bf16x8*>(&lds_w[(row << 12) + ((off ^ (row & 7)) << 4)]) = v;
        }
    }
    float bias_r[4];
    #pragma unroll
    for (int gi = 0; gi < 4; ++gi) {
        int R = gi * HID + gcol;
        bias_r[gi] = bx[l * G4 + R] + bh[l * G4 + R];
    }
    float c_reg = c0[(size_t)l * BH + (size_t)b_glob * HID + gcol];
    bf16_t* ringL = (l == 0) ? ring0 : ring1;
    __syncthreads();

    unsigned bargen = 0;

    for (int i = 0; i <= S_LEN; ++i) {
        const int  t      = (l == 0) ? i : (i - 1);
        const bool active = (l == 0) ? (i < S_LEN) : (i >= 1);
        if (active) {
            // x-part A source (bf16 unless layer-0 fallback), h-part A source
            const bf16_t* axb  = nullptr;
            const float*  ax32 = nullptr;
            if (l == 0) {
                if (use_xsh) axb = x_sh + (size_t)t * BH;
                else         ax32 = x + (size_t)t * BH;
            } else {
                axb = ring0 + (size_t)(t & 1) * BH;          // h^0[t], published last interval
            }
            const bf16_t* ah = ringL + (size_t)((t - 1) & 1) * BH;

            f32x4 acc = {0.f, 0.f, 0.f, 0.f};
            const unsigned char* bbase = &lds_w[r16 << 12];
            if (ax32) {
                const float* arow = ax32 + (size_t)(16 * wv + r16) * HID + quad * 8;
                #pragma unroll 4
                for (int kb = 0; kb < 32; ++kb) {
                    int gk = (kb << 2) + quad;
                    bf16x8 bfrag = *reinterpret_cast<const bf16x8*>(bbase + ((gk ^ swz) << 4));
                    bf16x8 afrag = cvt8(arow + (kb << 5));
                    acc = __builtin_amdgcn_mfma_f32_16x16x32_bf16(afrag, bfrag, acc, 0, 0, 0);
                }
            } else {
                const bf16_t* arow = axb + (size_t)(16 * wv + r16) * HID + quad * 8;
                #pragma unroll 4
                for (int kb = 0; kb < 32; ++kb) {
                    int gk = (kb << 2) + quad;
                    bf16x8 bfrag = *reinterpret_cast<const bf16x8*>(bbase + ((gk ^ swz) << 4));
                    bf16x8 afrag = *reinterpret_cast<const bf16x8*>(arow + (kb << 5));
                    acc = __builtin_amdgcn_mfma_f32_16x16x32_bf16(afrag, bfrag, acc, 0, 0, 0);
                }
            }
            {
                const bf16_t* hrow = ah + (size_t)(16 * wv + r16) * HID + quad * 8;
                #pragma unroll 4
                for (int kb = 0; kb < 32; ++kb) {
                    int gk = 128 + (kb << 2) + quad;
                    bf16x8 bfrag = *reinterpret_cast<const bf16x8*>(bbase + ((gk ^ swz) << 4));
                    bf16x8 afrag = *reinterpret_cast<const bf16x8*>(hrow + (kb << 5));
                    acc = __builtin_amdgcn_mfma_f32_16x16x32_bf16(afrag, bfrag, acc, 0, 0, 0);
                }
            }

            // gather 4 gates for (b_loc, uu): C layout col=lane&15, row=quad*4+reg
            const int quad_s = b_loc >> 2;
            const int reg_s  = b_loc & 3;
            float gsum[4];
            #pragma unroll
            for (int gi = 0; gi < 4; ++gi) {
                int lane_s = (quad_s << 4) | (4 * gi + uu);
                float v0 = __shfl(acc[0], lane_s, 64);
                float v1 = __shfl(acc[1], lane_s, 64);
                float v2 = __shfl(acc[2], lane_s, 64);
                float v3 = __shfl(acc[3], lane_s, 64);
                float v  = (reg_s == 0) ? v0 : (reg_s == 1) ? v1 : (reg_s == 2) ? v2 : v3;
                gsum[gi] = v + bias_r[gi];
            }
            float fg = sigmoid_f(gsum[0]);
            float ig = sigmoid_f(gsum[1]);
            float og = sigmoid_f(gsum[2]);
            float cx = tanh_f(gsum[3]);
            float cN = fg * c_reg + ig * cx;
            float h  = og * tanh_f(cN);
            c_reg = cN;

            ringL[(size_t)(t & 1) * BH + (size_t)b_glob * HID + gcol] = (bf16_t)h;
            if (l == 1) ys[(size_t)t * BH + (size_t)b_glob * HID + gcol] = h;
            if (t == S_LEN - 1) {
                hfin[(size_t)l * BH + (size_t)b_glob * HID + gcol] = h;
                cfin[(size_t)l * BH + (size_t)b_glob * HID + gcol] = cN;
            }
        }

        if (i < S_LEN) {
            // ---- single-stage grid barrier: everyone publishes, everyone polls all flags ----
            ++bargen;
            __syncthreads();
            if (tid == 0) {
                __builtin_amdgcn_fence(__ATOMIC_RELEASE, "agent");
                __hip_atomic_store(&flags[bid * FSTRIDE], bargen, __ATOMIC_RELAXED, __HIP_MEMORY_SCOPE_AGENT);
            }
            if (tid < 64) {
                for (;;) {
                    bool ok = true;
                    #pragma unroll
                    for (int j = 0; j < 8; ++j) {
                        unsigned m = __hip_atomic_load(&flags[(tid + 64 * j) * FSTRIDE],
                                                       __ATOMIC_RELAXED, __HIP_MEMORY_SCOPE_AGENT);
                        ok &= (m >= bargen);
                    }
                    if (__all(ok)) break;
                    __builtin_amdgcn_s_sleep(2);
                }
                __builtin_amdgcn_fence(__ATOMIC_ACQUIRE, "agent");
            }
            __syncthreads();
        }
    }
}

extern "C" void kernel_launch(void* const* d_in, const int* in_sizes, int n_in,
                              void* d_out, int out_size, void* d_ws, size_t ws_size,
                              hipStream_t stream) {
    (void)in_sizes; (void)n_in; (void)out_size;
    const float* x  = (const float*)d_in[0];
    const float* h0 = (const float*)d_in[1];
    const float* c0 = (const float*)d_in[2];
    const float* Wx = (const float*)d_in[3];
    const float* Wh = (const float*)d_in[4];
    const float* bx = (const float*)d_in[5];
    const float* bh = (const float*)d_in[6];

    unsigned char* ws = (unsigned char*)d_ws;
    unsigned* flags = (unsigned*)ws;                          // 512*16*4 = 32 KB
    size_t off = 32768;
    bf16_t* ring0 = (bf16_t*)(ws + off); off += (size_t)2 * BH * 2;   // 256 KB
    bf16_t* ring1 = (bf16_t*)(ws + off); off += (size_t)2 * BH * 2;   // 256 KB
    bf16_t* x_sh  = (bf16_t*)(ws + off);
    size_t need_xsh = off + (size_t)S_LEN * BH * 2;           // + 64 MB
    int use_xsh = (ws_size >= need_xsh) ? 1 : 0;

    prep_kernel<<<2048, 256, 0, stream>>>(x, h0, ring0, ring1, x_sh, flags, use_xsh);
    lstm_persistent<<<NBLK, NTHR, 0, stream>>>(x, c0, Wx, Wh, bx, bh,
                                               (float*)d_out, ring0, ring1, x_sh, flags, use_xsh);
}